// Round 1
// baseline (405.668 us; speedup 1.0000x reference)
//
#include <hip/hip_runtime.h>

// Unpool_LS: per 2x2 block (L=4) per channel:
//   v[l] = x0[b, 2i+p, 2j+q, c], l = p*2+q
//   sort desc -> sv; cs[k] = cumsum(sv)[k] + x1; avg[k] = cs[k]/(k+2)
//   repl = max(avg), k = first argmax
//   mask[l] = (stable descending rank of v[l]) <= k
//   out0[l] = mask ? repl : v[l];  out1 = repl;  out2[l] = mask ? (k+1)/(k+2) : 1
// Memory-bound: 448 MB total traffic, ~71 us floor at 6.3 TB/s.

namespace {
constexpr int NB = 8;
constexpr int H  = 256;
constexpr int W  = 256;
constexpr int C  = 64;
constexpr int h  = H / 2;   // 128
constexpr int w  = W / 2;   // 128
constexpr long long N0 = (long long)NB * H * W * C;  // 33554432 (out0)
constexpr long long N1 = (long long)NB * h * w * C;  //  8388608 (repl)
}

__global__ __launch_bounds__(256)
void unpool_ls_kernel(const float* __restrict__ x0, const float* __restrict__ x1,
                      float* __restrict__ out0, float* __restrict__ out1,
                      float* __restrict__ out2)
{
    const int t  = blockIdx.x * blockDim.x + threadIdx.x;
    // total threads = NB*h*w*(C/4) = 2,097,152
    const int c4 = t & 15;           // which float4 group of channels
    const int j  = (t >> 4) & (w - 1);
    const int i  = (t >> 11) & (h - 1);
    const int b  = t >> 18;

    const size_t rowS  = (size_t)W * C;                                   // row stride in x0
    const size_t base0 = ((size_t)((b * H + 2 * i) * W + 2 * j)) * C + c4 * 4;
    const size_t baseP = ((size_t)((b * h + i) * w + j)) * C + c4 * 4;

    // Block layout: l=0 -> (+0), l=1 -> (+C), l=2 -> (+rowS), l=3 -> (+rowS+C)
    const float4 v00 = *reinterpret_cast<const float4*>(x0 + base0);
    const float4 v01 = *reinterpret_cast<const float4*>(x0 + base0 + C);
    const float4 v10 = *reinterpret_cast<const float4*>(x0 + base0 + rowS);
    const float4 v11 = *reinterpret_cast<const float4*>(x0 + base0 + rowS + C);
    const float4 pv  = *reinterpret_cast<const float4*>(x1 + baseP);

    float va[4][4];   // [e = channel-in-group][l = block position]
    va[0][0] = v00.x; va[1][0] = v00.y; va[2][0] = v00.z; va[3][0] = v00.w;
    va[0][1] = v01.x; va[1][1] = v01.y; va[2][1] = v01.z; va[3][1] = v01.w;
    va[0][2] = v10.x; va[1][2] = v10.y; va[2][2] = v10.z; va[3][2] = v10.w;
    va[0][3] = v11.x; va[1][3] = v11.y; va[2][3] = v11.z; va[3][3] = v11.w;
    float pe[4] = {pv.x, pv.y, pv.z, pv.w};

    float ra[4][4];   // out0 values [e][l]
    float rf[4][4];   // out2 (fraction) values [e][l]
    float rp[4];      // repl per channel

#pragma unroll
    for (int e = 0; e < 4; ++e) {
        const float a0 = va[e][0], a1 = va[e][1], a2 = va[e][2], a3 = va[e][3];

        // 5-comparator descending sort network on values only
        float s0 = a0, s1 = a1, s2 = a2, s3 = a3, tmp;
        if (s0 < s1) { tmp = s0; s0 = s1; s1 = tmp; }
        if (s2 < s3) { tmp = s2; s2 = s3; s3 = tmp; }
        if (s0 < s2) { tmp = s0; s0 = s2; s2 = tmp; }
        if (s1 < s3) { tmp = s1; s1 = s3; s3 = tmp; }
        if (s1 < s2) { tmp = s1; s1 = s2; s2 = tmp; }

        // cumsum + x1, avg = cs/(k+2), first argmax (strict > keeps first)
        const float x1e = pe[e];
        float run  = s0;
        float best = (run + x1e) / 2.0f;
        int   k    = 0;
        run += s1; { const float c = (run + x1e) / 3.0f; if (c > best) { best = c; k = 1; } }
        run += s2; { const float c = (run + x1e) / 4.0f; if (c > best) { best = c; k = 2; } }
        run += s3; { const float c = (run + x1e) / 5.0f; if (c > best) { best = c; k = 3; } }

        // Stable descending rank of each position:
        // rank[l] = #{m : v[m] > v[l]} + #{m < l : v[m] == v[l]}
        const float frac = ((float)(k + 1)) / ((float)(k + 2));
#pragma unroll
        for (int l = 0; l < 4; ++l) {
            const float vl = va[e][l];
            int rank = 0;
#pragma unroll
            for (int m = 0; m < 4; ++m) {
                const float vm = va[e][m];
                rank += (vm > vl) ? 1 : ((vm == vl && m < l) ? 1 : 0);
            }
            const bool sel = (rank <= k);
            ra[e][l] = sel ? best : vl;
            rf[e][l] = sel ? frac : 1.0f;
        }
        rp[e] = best;
    }

    // Pack and store (same layout as the loads, per output tensor)
    float4 s;
    s.x = ra[0][0]; s.y = ra[1][0]; s.z = ra[2][0]; s.w = ra[3][0];
    *reinterpret_cast<float4*>(out0 + base0) = s;
    s.x = ra[0][1]; s.y = ra[1][1]; s.z = ra[2][1]; s.w = ra[3][1];
    *reinterpret_cast<float4*>(out0 + base0 + C) = s;
    s.x = ra[0][2]; s.y = ra[1][2]; s.z = ra[2][2]; s.w = ra[3][2];
    *reinterpret_cast<float4*>(out0 + base0 + rowS) = s;
    s.x = ra[0][3]; s.y = ra[1][3]; s.z = ra[2][3]; s.w = ra[3][3];
    *reinterpret_cast<float4*>(out0 + base0 + rowS + C) = s;

    s.x = rp[0]; s.y = rp[1]; s.z = rp[2]; s.w = rp[3];
    *reinterpret_cast<float4*>(out1 + baseP) = s;

    s.x = rf[0][0]; s.y = rf[1][0]; s.z = rf[2][0]; s.w = rf[3][0];
    *reinterpret_cast<float4*>(out2 + base0) = s;
    s.x = rf[0][1]; s.y = rf[1][1]; s.z = rf[2][1]; s.w = rf[3][1];
    *reinterpret_cast<float4*>(out2 + base0 + C) = s;
    s.x = rf[0][2]; s.y = rf[1][2]; s.z = rf[2][2]; s.w = rf[3][2];
    *reinterpret_cast<float4*>(out2 + base0 + rowS) = s;
    s.x = rf[0][3]; s.y = rf[1][3]; s.z = rf[2][3]; s.w = rf[3][3];
    *reinterpret_cast<float4*>(out2 + base0 + rowS + C) = s;
}

extern "C" void kernel_launch(void* const* d_in, const int* in_sizes, int n_in,
                              void* d_out, int out_size, void* d_ws, size_t ws_size,
                              hipStream_t stream) {
    const float* x0 = (const float*)d_in[0];
    const float* x1 = (const float*)d_in[1];
    float* out0 = (float*)d_out;          // [8,256,256,64]
    float* out1 = out0 + N0;              // [8,128,128,64]
    float* out2 = out1 + N1;              // [8,256,256,64]

    const int total  = NB * h * w * (C / 4);   // 2,097,152
    const int block  = 256;
    const int grid   = total / block;          // 8192
    hipLaunchKernelGGL(unpool_ls_kernel, dim3(grid), dim3(block), 0, stream,
                       x0, x1, out0, out1, out2);
}